// Round 11
// baseline (517.940 us; speedup 1.0000x reference)
//
#include <hip/hip_runtime.h>
#include <math.h>

#define NROWS 32768
#define DDIM 256
#define KEMB 1024

#define OFF_COMMIT 8388608
#define OFF_EMBED  8388609
#define OFF_ENT    8388610
#define OFF_IDX    8388611

// ws float layout: [0..1023] avg_prob sums, [1024] H sum, [1025] sqdiff sum,
// [1026..2049] cnorm. (img eliminated this round: B-feed reads cb directly)

// prevent -ffp-contract=fast from fusing this mul into a following add
#define NOFUSE(x) asm volatile("" : "+v"(x))

typedef __attribute__((ext_vector_type(8))) short bf16x8;
typedef __attribute__((ext_vector_type(16))) float f32x16;
#define MFMA32(a, b, c) __builtin_amdgcn_mfma_f32_32x32x16_bf16((a), (b), (c), 0, 0, 0)

// round-to-nearest-even fp32 -> bf16 hi + bf16 lo split
__device__ inline void bf16split(float x, unsigned short& h, unsigned short& l) {
  unsigned u = __float_as_uint(x);
  unsigned r = u + 0x7FFFu + ((u >> 16) & 1u);
  h = (unsigned short)(r >> 16);
  float hf = __uint_as_float(r & 0xFFFF0000u);
  float lo = x - hf;  // exact (Sterbenz)
  unsigned ul = __float_as_uint(lo);
  unsigned rl = ul + 0x7FFFu + ((ul >> 16) & 1u);
  l = (unsigned short)(rl >> 16);
}

// ---- cnorm: emulate np.sum(cb**2, axis=1) pairwise order bit-exactly ----
__global__ __launch_bounds__(256) void vq_pre1(const float* __restrict__ cb,
                                               float* __restrict__ ws) {
  int t = blockIdx.x * 256 + threadIdx.x;  // 64 blocks -> [0,16384)
  if (t < 1026) ws[t] = 0.0f;
  int row = t >> 4;  // 0..1023
  int l = t & 15;
  int h = l >> 3, j = l & 7;
  const float* xp = cb + (size_t)row * DDIM + h * 128 + j;
  float x = xp[0];
  float sq = x * x; NOFUSE(sq);
  float r = sq;
#pragma unroll
  for (int tt = 1; tt < 16; ++tt) {
    x = xp[8 * tt];
    sq = x * x; NOFUSE(sq);
    r = r + sq;
  }
  r = r + __shfl_xor(r, 1, 64);
  r = r + __shfl_xor(r, 2, 64);
  r = r + __shfl_xor(r, 4, 64);
  r = r + __shfl_xor(r, 8, 64);
  if (l == 0) ws[1026 + row] = r;
}

// ---- MFMA main v6: identical to verified v5 EXCEPT the B-feed reads cb
// (d_in, cached) directly as fp32 and does the bf16 hi/lo split on the fly.
// PERSISTENT: grid=256 (1/CU), 4 tiles of 32 rows; 1024 threads (16 waves),
// 2 col-tiles/wave; one global-atomic set per block.
// LDS 100.2KB: pacc@0 (4K), zh@4K (16K), zl@20K (16K), logits@36K (64K),
// redH/redS@100K.
__global__ __launch_bounds__(1024, 4) void vq_main6(const float* __restrict__ z,
                                                    const float* __restrict__ cb,
                                                    float* __restrict__ out,
                                                    float* __restrict__ ws) {
  __shared__ __align__(16) unsigned char smem[102656];
  float* pacc = (float*)smem;                          // 1024 f, persistent
  unsigned short* zh_s = (unsigned short*)(smem + 4096);
  unsigned short* zl_s = (unsigned short*)(smem + 20480);
  float* logits = (float*)(smem + 36864);              // [16][1024]
  float* redH = (float*)(smem + 102400);               // 16 f
  float* redS = (float*)(smem + 102464);               // 16 f

  const int tid = threadIdx.x;
  const int w = tid >> 6;          // wave 0..15
  const int lane = tid & 63;
  const int l31 = lane & 31, lhi = lane >> 5;
  const float* cnorm = ws + 1026;
  const int ct0 = w * 2, ct1 = w * 2 + 1;
  const float cn0 = cnorm[ct0 * 32 + l31];
  const float cn1 = cnorm[ct1 * 32 + l31];
  const int erow = tid >> 6, ecl = tid & 63;
  // per-lane cb base pointers for the B fragments (row = col-tile*32 + l31)
  const float* cbp0 = cb + (size_t)(ct0 * 32 + l31) * 256 + lhi * 8;
  const float* cbp1 = cb + (size_t)(ct1 * 32 + l31) * 256 + lhi * 8;

  pacc[tid] = 0.0f;   // ordered vs first reads by the post-staging barrier
  float hacc = 0.0f, sqacc = 0.0f;

#pragma unroll 1
  for (int t = 0; t < 4; ++t) {
    const int nbase = (blockIdx.x * 4 + t) * 32;

    // stage z rows 0..31: fp32 -> bf16 hi/lo, XOR-swizzled 16B units
#pragma unroll
    for (int i = 0; i < 8; ++i) {
      int idx = tid + (i << 10);
      int row = idx >> 8, k = idx & 255;
      float x = z[((size_t)(nbase + row) << 8) + k];
      unsigned short hh, ll;
      bf16split(x, hh, ll);
      int uoff = (row << 8) | ((((k >> 3) ^ row) & 31) << 3) | (k & 7);
      zh_s[uoff] = hh; zl_s[uoff] = ll;
    }
    __syncthreads();  // staging visible; also orders prev-tile epilogue reads

    f32x16 acc0, acc1;
#pragma unroll
    for (int e = 0; e < 16; ++e) { acc0[e] = 0.0f; acc1[e] = 0.0f; }

#pragma unroll 1
    for (int kc = 0; kc < 16; ++kc) {
      // A-frags from LDS (XOR-swizzled, same as verified)
      const int au = (l31 << 8) | (((((kc << 1) | lhi) ^ l31) & 31) << 3);
      bf16x8 azh = *(const bf16x8*)(zh_s + au);
      bf16x8 azl = *(const bf16x8*)(zl_s + au);
      // B-frags: fp32 from cb + on-the-fly split (same k-order as img path:
      // element j = cb[ct*32+l31][kc*16+lhi*8+j])
      const float* s0 = cbp0 + kc * 16;
      const float* s1 = cbp1 + kc * 16;
      float4 a0 = *(const float4*)(s0);
      float4 a1 = *(const float4*)(s0 + 4);
      float4 b0 = *(const float4*)(s1);
      float4 b1 = *(const float4*)(s1 + 4);
      bf16x8 bh0, bl0, bh1, bl1;
      unsigned short hh, ll;
      bf16split(a0.x, hh, ll); bh0[0] = hh; bl0[0] = ll;
      bf16split(a0.y, hh, ll); bh0[1] = hh; bl0[1] = ll;
      bf16split(a0.z, hh, ll); bh0[2] = hh; bl0[2] = ll;
      bf16split(a0.w, hh, ll); bh0[3] = hh; bl0[3] = ll;
      bf16split(a1.x, hh, ll); bh0[4] = hh; bl0[4] = ll;
      bf16split(a1.y, hh, ll); bh0[5] = hh; bl0[5] = ll;
      bf16split(a1.z, hh, ll); bh0[6] = hh; bl0[6] = ll;
      bf16split(a1.w, hh, ll); bh0[7] = hh; bl0[7] = ll;
      bf16split(b0.x, hh, ll); bh1[0] = hh; bl1[0] = ll;
      bf16split(b0.y, hh, ll); bh1[1] = hh; bl1[1] = ll;
      bf16split(b0.z, hh, ll); bh1[2] = hh; bl1[2] = ll;
      bf16split(b0.w, hh, ll); bh1[3] = hh; bl1[3] = ll;
      bf16split(b1.x, hh, ll); bh1[4] = hh; bl1[4] = ll;
      bf16split(b1.y, hh, ll); bh1[5] = hh; bl1[5] = ll;
      bf16split(b1.z, hh, ll); bh1[6] = hh; bl1[6] = ll;
      bf16split(b1.w, hh, ll); bh1[7] = hh; bl1[7] = ll;
      // split-bf16 3-pass MFMA, acc0/acc1 interleaved (dep distance 2)
      acc0 = MFMA32(azh, bh0, acc0);
      acc1 = MFMA32(azh, bh1, acc1);
      acc0 = MFMA32(azh, bl0, acc0);
      acc1 = MFMA32(azh, bl1, acc1);
      acc0 = MFMA32(azl, bh0, acc0);
      acc1 = MFMA32(azl, bh1, acc1);
    }

    // ---- per-tile epilogue: 2 groups of 16 rows, 64 lanes per row ----
#pragma unroll
    for (int g = 0; g < 2; ++g) {
      __syncthreads();  // prev-group logits reads done before rewrite
#pragma unroll
      for (int q = 0; q < 8; ++q) {
        int reg = q + (g << 3);
        int r16 = (q & 3) | ((q >> 2) << 3) | (lhi << 2);
        logits[(r16 << 10) + ct0 * 32 + l31] = 200.0f * acc0[reg] - 100.0f * cn0;
        logits[(r16 << 10) + ct1 * 32 + l31] = 200.0f * acc1[reg] - 100.0f * cn1;
      }
      __syncthreads();
      const int grow = nbase + (g << 4) + erow;
      float v2[16];  // cols ecl + 64m, ascending
#pragma unroll
      for (int m = 0; m < 16; ++m) v2[m] = logits[(erow << 10) + ecl + (m << 6)];
      // top-2 argmax (== argmin distance), tie -> smaller index
      float m1 = -3.4e38f, m2v = -3.4e38f;
      int c1 = 0;
#pragma unroll
      for (int m = 0; m < 16; ++m) {
        float val = v2[m];
        if (val > m1) { m2v = m1; m1 = val; c1 = ecl + (m << 6); }
        else if (val > m2v) { m2v = val; }
      }
#pragma unroll
      for (int mk = 1; mk < 64; mk <<= 1) {
        float om1 = __shfl_xor(m1, mk, 64);
        int oc1 = __shfl_xor(c1, mk, 64);
        float om2 = __shfl_xor(m2v, mk, 64);
        if (om1 > m1 || (om1 == m1 && oc1 < c1)) { m2v = fmaxf(m1, om2); m1 = om1; c1 = oc1; }
        else { m2v = fmaxf(om1, m2v); }
      }
      const float rowmax = m1;
      const int bcol = c1;
      const bool danger = (m1 - m2v) < 0.25f;  // ~2500x MFMA-path error bound
      // softmax stats
      float S = 0.f, T = 0.f;
#pragma unroll
      for (int m = 0; m < 16; ++m) {
        float e = __expf(v2[m] - rowmax);
        S += e;
        T = fmaf(e, v2[m], T);
        v2[m] = e;
      }
#pragma unroll
      for (int mk = 1; mk < 64; mk <<= 1) {
        S += __shfl_xor(S, mk, 64);
        T += __shfl_xor(T, mk, 64);
      }
      const float invZ = 1.0f / S;
      const float H = rowmax + logf(S) - T * invZ;
#pragma unroll
      for (int m = 0; m < 16; ++m) atomicAdd(&pacc[ecl + (m << 6)], v2[m] * invZ);
      // quantized write (straight-through, exact ref op order) + sqdiff
      float sq = 0.f;
      {
        const float* zr = z + ((size_t)grow << 8) + (ecl << 2);
        const float* cr = cb + ((size_t)bcol << 8) + (ecl << 2);
        float* orow = out + ((size_t)grow << 8) + (ecl << 2);
        float4 zv = *(const float4*)(zr);
        float4 cv = *(const float4*)(cr);
        float4 qv;
        qv.x = zv.x + (cv.x - zv.x);
        qv.y = zv.y + (cv.y - zv.y);
        qv.z = zv.z + (cv.z - zv.z);
        qv.w = zv.w + (cv.w - zv.w);
        *(float4*)(orow) = qv;
        float dx = cv.x - zv.x; sq = fmaf(dx, dx, sq);
        dx = cv.y - zv.y; sq = fmaf(dx, dx, sq);
        dx = cv.z - zv.z; sq = fmaf(dx, dx, sq);
        dx = cv.w - zv.w; sq = fmaf(dx, dx, sq);
      }
#pragma unroll
      for (int mk = 1; mk < 64; mk <<= 1) sq += __shfl_xor(sq, mk, 64);
      if (ecl == 0) {
        hacc += H;
        sqacc += sq;
        out[OFF_IDX + grow] = danger ? -(float)(bcol + 1) : (float)bcol;
      }
    }
  }

  // ---- ONE set of global atomics per block ----
  if (ecl == 0) { redH[erow] = hacc; redS[erow] = sqacc; }
  __syncthreads();
  atomicAdd(&ws[tid], pacc[tid]);
  if (tid == 0) {
    float hs = 0.f, ss = 0.f;
#pragma unroll
    for (int i = 0; i < 16; ++i) { hs += redH[i]; ss += redS[i]; }
    atomicAdd(&ws[1024], hs);
    atomicAdd(&ws[1025], ss);
  }
}

// ---- fused tail ----
// blocks 0..255: ballot-scan re-resolve of contested rows (bit-level numpy
// emulation; each wave owns 32 rows). block 256: final loss reduction.
__global__ __launch_bounds__(256) void vq_fixfinal(const float* __restrict__ z,
                                                   const float* __restrict__ cb,
                                                   float* __restrict__ out,
                                                   const float* __restrict__ ws) {
  if (blockIdx.x == 256) {
    __shared__ float red[256];
    int t = threadIdx.x;
    float s = 0.f;
#pragma unroll
    for (int i = 0; i < 4; ++i) {
      float a = ws[t + i * 256] * (1.0f / 32768.0f);
      s += a * logf(a + 1e-5f);
    }
    red[t] = s;
    __syncthreads();
    for (int st = 128; st > 0; st >>= 1) {
      if (t < st) red[t] += red[t + st];
      __syncthreads();
    }
    if (t == 0) {
      float avg_entropy = -red[0];
      float sample_entropy = ws[1024] * (1.0f / 32768.0f);
      float m = ws[1025] * (1.0f / 8388608.0f);
      out[OFF_COMMIT] = 0.25f * m;
      out[OFF_EMBED] = m;
      out[OFF_ENT] = 0.1f * (sample_entropy - avg_entropy);
    }
    return;
  }

  const int lane = threadIdx.x & 63;
  const int gwave = (int)((blockIdx.x * 256 + threadIdx.x) >> 6);  // 0..1023
  const int rbase = gwave * 32;
  const float* cnorm = ws + 1026;

  float iv = (lane < 32) ? out[OFF_IDX + rbase + lane] : 0.0f;
  unsigned long long mask = __ballot(iv < 0.0f);
  while (mask) {
    int bit = __ffsll((long long)mask) - 1;
    mask &= mask - 1;
    int row = rbase + bit;
    float ivr = __shfl(iv, bit, 64);
    int kold = (int)(-ivr) - 1;
    const float* zr = z + (size_t)row * DDIM;

    // znorm, numpy pairwise (lanes 0..15 carry the 16 accumulators)
    float r;
    {
      int h = (lane & 15) >> 3, j = lane & 7;
      const float* xp = zr + h * 128 + j;
      float x = xp[0];
      float sq = x * x; NOFUSE(sq);
      r = sq;
#pragma unroll
      for (int tt = 1; tt < 16; ++tt) {
        x = xp[8 * tt];
        sq = x * x; NOFUSE(sq);
        r = r + sq;
      }
    }
    r = r + __shfl_xor(r, 1, 64);
    r = r + __shfl_xor(r, 2, 64);
    r = r + __shfl_xor(r, 4, 64);
    r = r + __shfl_xor(r, 8, 64);
    const float znorm = __shfl(r, 0, 64);

    // emulated distances: dot = sequential ascending-k fp32 FMA chain
    float bd = 3.4e38f;
    int bk = 0;
#pragma unroll 1
    for (int t = 0; t < 16; ++t) {
      int k = lane + t * 64;
      const float* cr = cb + (size_t)k * DDIM;
      float acc = 0.0f;
#pragma unroll 8
      for (int d = 0; d < 256; ++d) acc = fmaf(zr[d], cr[d], acc);
      float dist = (znorm - 2.0f * acc) + cnorm[k];
      if (dist < bd) { bd = dist; bk = k; }
    }
#pragma unroll
    for (int m = 1; m < 64; m <<= 1) {
      float od = __shfl_xor(bd, m, 64);
      int ok = __shfl_xor(bk, m, 64);
      if (od < bd || (od == bd && ok < bk)) { bd = od; bk = ok; }
    }

    if (bk != kold) {
      const float* cr = cb + (size_t)bk * DDIM;
#pragma unroll
      for (int i = 0; i < 4; ++i) {
        int d0 = lane + i * 64;
        float zd = zr[d0], cd = cr[d0];
        out[(size_t)row * DDIM + d0] = zd + (cd - zd);
      }
    }
    if (lane == 0) out[OFF_IDX + row] = (float)bk;
  }
}

extern "C" void kernel_launch(void* const* d_in, const int* in_sizes, int n_in,
                              void* d_out, int out_size, void* d_ws, size_t ws_size,
                              hipStream_t stream) {
  const float* z = (const float*)d_in[0];
  const float* cb = (const float*)d_in[1];
  float* out = (float*)d_out;
  float* ws = (float*)d_ws;

  vq_pre1<<<64, 256, 0, stream>>>(cb, ws);
  vq_main6<<<256, 1024, 0, stream>>>(z, cb, out, ws);
  vq_fixfinal<<<257, 256, 0, stream>>>(z, cb, out, ws);
}